// Round 9
// baseline (179.130 us; speedup 1.0000x reference)
//
#include <hip/hip_runtime.h>

// FernSparseTable: B[64,160,32,32] f32, tables[16,1024,64] f32,
// out[64,32,32,64] f32 = sum over 16 ferns of 8-word weighted table gathers.
//
// Round-9 = resubmission (infra timeouts r6/r7/r8; design unmeasured).
// LDS-staged table gathers (round-3 counters showed the TA/L1
// line-serialization path was the bottleneck; LDS serves random 16B reads
// bank-parallel).
//   - d-split 8: block owns d = dq*8 .. dq*8+7. Fern slice = 1024x32B = 32KB.
//   - double-buffered LDS (2x32KB), prefetch fern m+1 during fern m.
//   - block = 1024 threads = 1024 pixels (one image n), grid = 64 x 8 = 512.
//     dq = bid>>6, pg = bid&63 -> the 8 blocks sharing B differ by 64 = same XCD.
//   - staging: global_load_lds width 16, LDS dest linear (t*16), global source
//     pre-swizzled; reads apply the same involution (both-sides-or-neither).
//   - swizzle: stored slot jj of row r holds source float4 (jj ^ ((r>>2)&1));
//     read of source slot j uses stored slot j ^ ((it>>2)&1).
//     Banks per instr: (it&3)*8 + slot*4 -> all 8 bank-quads covered.

#define NFERN 16
#define KBITS 10

typedef __attribute__((address_space(1))) const void GV;
typedef __attribute__((address_space(3))) void LV;
__device__ __forceinline__ void g2lds16(const void* g, void* l) {
    __builtin_amdgcn_global_load_lds((GV*)g, (LV*)l, 16u, 0, 0u);
}

__global__ __launch_bounds__(1024, 8)
void fern_kernel(const float* __restrict__ B,
                 const float* __restrict__ tables,
                 float* __restrict__ out) {
    __shared__ __align__(16) float lds[2][1024 * 8];   // 2 x 32KB

    const int t   = (int)threadIdx.x;
    const int bid = (int)blockIdx.x;
    const int pg  = bid & 63;            // pixel group == image index n
    const int dq  = bid >> 6;            // d-octant: owns d = dq*8 .. +7
    const int pixel = pg * 1024 + t;

    const float* bptr = B + (size_t)pg * (NFERN * KBITS * 1024) + t;
    const float* tq   = tables + dq * 8;

    // staging: thread t covers rows r = R*512 + (t>>1), stored slot jj = t&1,
    // source float4-slot sl = jj ^ ((r>>2)&1) = (t&1) ^ ((t>>3)&1)
    const int st_sl = (t & 1) ^ ((t >> 3) & 1);

    float4 acc0 = make_float4(0.f, 0.f, 0.f, 0.f);
    float4 acc1 = make_float4(0.f, 0.f, 0.f, 0.f);

    // ---- prologue: stage fern 0 into buffer 0 ----
    {
        const float* base = tq;
        #pragma unroll
        for (int R = 0; R < 2; ++R) {
            const int r = R * 512 + (t >> 1);
            g2lds16(base + (size_t)r * 64 + st_sl * 4,
                    (char*)(&lds[0][0]) + R * 16384 + t * 16);
        }
    }
    __syncthreads();   // drains vmcnt -> buf0 ready

    #pragma unroll 1
    for (int m = 0; m < NFERN; ++m) {
        // ---- prefetch fern m+1 into the other buffer ----
        if (m + 1 < NFERN) {
            const float* base = tq + (size_t)(m + 1) * (1024 * 64);
            const int buf = (m + 1) & 1;
            #pragma unroll
            for (int R = 0; R < 2; ++R) {
                const int r = R * 512 + (t >> 1);
                g2lds16(base + (size_t)r * 64 + st_sl * 4,
                        (char*)(&lds[buf][0]) + R * 16384 + t * 16);
            }
        }
        const float* L = &lds[m & 1][0];

        // ---- 10 bit probabilities (coalesced, 256B/wave) ----
        float tk[KBITS];
        #pragma unroll
        for (int k = 0; k < KBITS; ++k)
            tk[k] = bptr[(m * KBITS + k) * 1024];

        // ---- base word ----
        unsigned wb = 0u;
        #pragma unroll
        for (int k = 0; k < KBITS; ++k)
            wb = (wb << 1) | (tk[k] > 0.5f ? 1u : 0u);   // round-half-even: 0.5 -> 0

        // ---- three argmin passes (first-occurrence ties, exclude by index) ----
        int i0, i1, i2;
        float p0, p1, p2;
        {
            float bv = 1e30f; int bi = 0; float bpv = 0.f;
            #pragma unroll
            for (int k = 0; k < KBITS; ++k) {
                float v = fabsf(tk[k] - 0.5f);
                bool c = v < bv;
                bv = c ? v : bv;  bi = c ? k : bi;  bpv = c ? tk[k] : bpv;
            }
            i0 = bi; p0 = bpv;
        }
        {
            float bv = 1e30f; int bi = 0; float bpv = 0.f;
            #pragma unroll
            for (int k = 0; k < KBITS; ++k) {
                float v = (k == i0) ? 1e30f : fabsf(tk[k] - 0.5f);
                bool c = v < bv;
                bv = c ? v : bv;  bi = c ? k : bi;  bpv = c ? tk[k] : bpv;
            }
            i1 = bi; p1 = bpv;
        }
        {
            float bv = 1e30f; int bi = 0; float bpv = 0.f;
            #pragma unroll
            for (int k = 0; k < KBITS; ++k) {
                float v = (k == i0 || k == i1) ? 1e30f : fabsf(tk[k] - 0.5f);
                bool c = v < bv;
                bv = c ? v : bv;  bi = c ? k : bi;  bpv = c ? tk[k] : bpv;
            }
            i2 = bi; p2 = bpv;
        }

        const unsigned m0 = 1u << (KBITS - 1 - i0);
        const unsigned m1 = 1u << (KBITS - 1 - i1);
        const unsigned m2 = 1u << (KBITS - 1 - i2);
        const float q0 = 1.f - p0, q1 = 1.f - p1, q2 = 1.f - p2;

        // ---- 8 active words: swizzled LDS gather + weighted accumulate ----
        #pragma unroll
        for (int a = 0; a < 8; ++a) {
            unsigned it = wb;
            float at = 1.f;
            if (a & 1) { it |= m0; at *= p0; } else { it &= ~m0; at *= q0; }
            if (a & 2) { it |= m1; at *= p1; } else { it &= ~m1; at *= q1; }
            if (a & 4) { it |= m2; at *= p2; } else { it &= ~m2; at *= q2; }
            const int   bswz = (int)((it >> 2) & 1u);
            const float* rowp = L + it * 8;
            // stored slot bswz   holds source float4 j=0
            // stored slot 1^bswz holds source float4 j=1
            float4 v0 = *(const float4*)(rowp + bswz * 4);
            float4 v1 = *(const float4*)(rowp + (1 ^ bswz) * 4);
            acc0.x = fmaf(at, v0.x, acc0.x);
            acc0.y = fmaf(at, v0.y, acc0.y);
            acc0.z = fmaf(at, v0.z, acc0.z);
            acc0.w = fmaf(at, v0.w, acc0.w);
            acc1.x = fmaf(at, v1.x, acc1.x);
            acc1.y = fmaf(at, v1.y, acc1.y);
            acc1.z = fmaf(at, v1.z, acc1.z);
            acc1.w = fmaf(at, v1.w, acc1.w);
        }

        __syncthreads();   // reads of buf[m&1] done; prefetch of buf[(m+1)&1] landed
    }

    // ---- store out[pixel, dq*8 .. dq*8+7] ----
    float* op = out + (size_t)pixel * 64 + dq * 8;
    *(float4*)op       = acc0;
    *(float4*)(op + 4) = acc1;
}

extern "C" void kernel_launch(void* const* d_in, const int* in_sizes, int n_in,
                              void* d_out, int out_size, void* d_ws, size_t ws_size,
                              hipStream_t stream) {
    const float* B      = (const float*)d_in[0];
    const float* tables = (const float*)d_in[1];
    float* out          = (float*)d_out;
    fern_kernel<<<dim3(512), dim3(1024), 0, stream>>>(B, tables, out);
}